// Round 4
// baseline (6846.751 us; speedup 1.0000x reference)
//
#include <hip/hip_runtime.h>
#include <hip/hip_bf16.h>
#include <math.h>
#include <stdint.h>

// CoAtNet transformer block, MI355X. R4: diagnostic-correct baseline.
// Naive (no-MFMA) pipeline, templated on input dtype (bf16 vs fp32), with an
// on-device dtype detector choosing which variant runs. Goal: first PASS +
// determine actual harness dtype + get first rocprof counters.

typedef __bf16 bf16;

#define NN 784      // H*W tokens
#define CC 512      // channels
#define NHEADS 16
#define DHEAD 32
#define FFD 2048
#define NBATCH 16
#define NREL 1596

// ---------------------------------------------------------------------------
// Dtype detector: looks at 1024 words of x. If data is bf16, BOTH 16-bit
// halves of each word are bf16 samples of ~N(0,1): exponent in [90,140] (or 0).
// If data is fp32, the LOWER half is mantissa garbage: ~20% plausible.
// flag = 1 (bf16) if >= 75% of lower halves plausible, else 0 (fp32).
// ---------------------------------------------------------------------------
__global__ __launch_bounds__(256) void detect_dtype(const unsigned int* xw, int* flag)
{
  __shared__ int cnt[256];
  int plausible = 0;
  for (int i = threadIdx.x; i < 1024; i += 256) {
    unsigned w = xw[i];
    unsigned lo = w & 0xFFFFu;
    unsigned e = (lo >> 7) & 0xFFu;
    if (lo == 0u || (e >= 90u && e <= 140u)) plausible++;
  }
  cnt[threadIdx.x] = plausible;
  __syncthreads();
  if (threadIdx.x == 0) {
    int tot = 0;
    for (int i = 0; i < 256; i++) tot += cnt[i];
    flag[0] = (tot >= 768) ? 1 : 0;   // 75% of 1024
  }
}

// ---------------------------------------------------------------------------
// LayerNorm: x (b,C,N) -> xn (b,N,C). One block per (b,n) token.
// ---------------------------------------------------------------------------
template <typename T, int WANT>
__global__ __launch_bounds__(256) void ln_naive(
    const T* __restrict__ x, const T* __restrict__ lnw, const T* __restrict__ lnb,
    T* __restrict__ xn, const int* __restrict__ flag)
{
  if (flag[0] != WANT) return;
  int bn = blockIdx.x;
  int b = bn / NN, n = bn - b * NN;
  const T* xb = x + (size_t)b * CC * NN + n;
  int t = threadIdx.x;
  float v0 = (float)xb[(size_t)t * NN];
  float v1 = (float)xb[(size_t)(t + 256) * NN];
  float s = v0 + v1, ss = v0 * v0 + v1 * v1;
  #pragma unroll
  for (int m = 32; m >= 1; m >>= 1) {
    s  += __shfl_xor(s,  m);
    ss += __shfl_xor(ss, m);
  }
  __shared__ float red[2][4];
  int w = t >> 6, l = t & 63;
  if (l == 0) { red[0][w] = s; red[1][w] = ss; }
  __syncthreads();
  float S  = red[0][0] + red[0][1] + red[0][2] + red[0][3];
  float SS = red[1][0] + red[1][1] + red[1][2] + red[1][3];
  float mu  = S * (1.f / 512.f);
  float var = SS * (1.f / 512.f) - mu * mu;
  float rstd = rsqrtf(var + 1e-5f);
  T* o = xn + (size_t)bn * CC;
  o[t]       = (T)(((v0 - mu) * rstd) * (float)lnw[t]       + (float)lnb[t]);
  o[t + 256] = (T)(((v1 - mu) * rstd) * (float)lnw[t + 256] + (float)lnb[t + 256]);
}

// ---------------------------------------------------------------------------
// Naive LDS-tiled GEMM: out(act,res) = A (M=784 x KD, row-major) @ W (KD x NOUT,
// row-major, NO transpose) + bias. 16x16 tile, one output/thread, fp32 acc.
// ACT: 0 none, 1 exact gelu. RESM: 0 none, 1 +extra[(b,C,N)], 2 +extra[(b,N,C)].
// OUTM: 0 out (b,N,NOUT), 1 out (b,NOUT,N).
// ---------------------------------------------------------------------------
template <typename T, int NOUT, int KD, int ACT, int RESM, int OUTM, int WANT>
__global__ __launch_bounds__(256) void gemm_naive(
    const T* __restrict__ A, const T* __restrict__ W, const T* __restrict__ bias,
    T* __restrict__ out, const T* __restrict__ extra, const int* __restrict__ flag)
{
  if (flag[0] != WANT) return;
  __shared__ float a_t[16][17];
  __shared__ float w_t[16][17];
  int tx = threadIdx.x & 15, ty = threadIdx.x >> 4;
  int m0 = blockIdx.y * 16, bz = blockIdx.z;
  int mg = m0 + ty;
  int jg = blockIdx.x * 16 + tx;
  int ar = mg < NN ? mg : NN - 1;
  const T* Ab = A + (size_t)bz * NN * KD;
  float acc = 0.f;
  for (int k0 = 0; k0 < KD; k0 += 16) {
    a_t[ty][tx] = (float)Ab[(size_t)ar * KD + k0 + tx];
    w_t[ty][tx] = (float)W[(size_t)(k0 + ty) * NOUT + jg];
    __syncthreads();
    #pragma unroll
    for (int kk = 0; kk < 16; kk++)
      acc += a_t[ty][kk] * w_t[kk][tx];
    __syncthreads();
  }
  if (mg >= NN) return;
  acc += (float)bias[jg];
  if (ACT == 1) acc = 0.5f * acc * (1.f + erff(acc * 0.70710678118654752f));
  if (RESM == 1) acc += (float)extra[((size_t)bz * CC + jg) * NN + mg];
  if (RESM == 2) acc += (float)extra[((size_t)bz * NN + mg) * CC + jg];
  if (OUTM == 0) out[((size_t)bz * NN + mg) * NOUT + jg] = (T)acc;
  else           out[((size_t)bz * NOUT + jg) * NN + mg] = (T)acc;
}

// ---------------------------------------------------------------------------
// Naive attention, two-pass (recompute scores), one thread per query row.
// q,k,v in (b,N,C) layout (channel c = h*32+d). Bias: rel_bias[h][rel_idx[i,j]].
// No 1/sqrt(d) scaling (per reference). attn_out (b,N,C).
// ---------------------------------------------------------------------------
template <typename T, int WANT>
__global__ __launch_bounds__(256) void attn_naive(
    const T* __restrict__ q, const T* __restrict__ k, const T* __restrict__ v,
    const T* __restrict__ rel_bias, const int* __restrict__ rel_idx,
    T* __restrict__ attn_out, const int* __restrict__ flag)
{
  if (flag[0] != WANT) return;
  int i = blockIdx.x * 256 + threadIdx.x;
  int h = blockIdx.y, b = blockIdx.z;
  if (i >= NN) return;
  const T* qr = q + ((size_t)b * NN + i) * CC + h * DHEAD;
  float qv[DHEAD];
  #pragma unroll
  for (int d = 0; d < DHEAD; d++) qv[d] = (float)qr[d];
  const int* ridx = rel_idx + (size_t)i * NN;
  const T* rb = rel_bias + (size_t)h * NREL;
  const T* kb = k + (size_t)b * NN * CC + h * DHEAD;
  const T* vb = v + (size_t)b * NN * CC + h * DHEAD;

  float m = -1e30f;
  for (int j = 0; j < NN; j++) {
    const T* kr = kb + (size_t)j * CC;
    float s = 0.f;
    #pragma unroll
    for (int d = 0; d < DHEAD; d++) s += qv[d] * (float)kr[d];
    s += (float)rb[ridx[j]];
    m = fmaxf(m, s);
  }
  float l = 0.f;
  float o[DHEAD];
  #pragma unroll
  for (int d = 0; d < DHEAD; d++) o[d] = 0.f;
  for (int j = 0; j < NN; j++) {
    const T* kr = kb + (size_t)j * CC;
    float s = 0.f;
    #pragma unroll
    for (int d = 0; d < DHEAD; d++) s += qv[d] * (float)kr[d];
    s += (float)rb[ridx[j]];
    float p = __expf(s - m);
    l += p;
    const T* vr = vb + (size_t)j * CC;
    #pragma unroll
    for (int d = 0; d < DHEAD; d++) o[d] += p * (float)vr[d];
  }
  float inv = 1.f / l;
  T* op = attn_out + ((size_t)b * NN + i) * CC + h * DHEAD;
  #pragma unroll
  for (int d = 0; d < DHEAD; d++) op[d] = (T)(o[d] * inv);
}

// ---------------------------------------------------------------------------
template <typename T, int WANT>
static void run_pipeline(void* const* d_in, void* d_out, char* buf, int Bc,
                         const int* flag, hipStream_t stream)
{
  const T* x    = (const T*)d_in[0];
  const T* lnw  = (const T*)d_in[1];
  const T* lnb  = (const T*)d_in[2];
  const T* Wq   = (const T*)d_in[3];
  const T* bq   = (const T*)d_in[4];
  const T* Wk   = (const T*)d_in[5];
  const T* bk   = (const T*)d_in[6];
  const T* Wv   = (const T*)d_in[7];
  const T* bv   = (const T*)d_in[8];
  const T* Wo   = (const T*)d_in[9];
  const T* bo   = (const T*)d_in[10];
  const T* relb = (const T*)d_in[11];
  const T* W1   = (const T*)d_in[12];
  const T* b1   = (const T*)d_in[13];
  const T* W2   = (const T*)d_in[14];
  const T* b2   = (const T*)d_in[15];
  const int* reli = (const int*)d_in[16];
  T* outp = (T*)d_out;

  const size_t TOK   = (size_t)NN * CC;
  const size_t FFTOK = (size_t)NN * FFD;
  // Regions are sized in BYTES for fp32 (worst case); both variants share them.
  T* xn  = (T*)(buf);
  T* qb  = (T*)(buf + (size_t)Bc * TOK * 4);
  T* kb  = (T*)(buf + 2 * (size_t)Bc * TOK * 4);
  T* vb  = (T*)(buf + 3 * (size_t)Bc * TOK * 4);
  T* ff1 = (T*)(buf + 4 * (size_t)Bc * TOK * 4);
  T* attn_out = xn;  // xn dead after QKV
  T* x1 = qb;        // q dead after attention

  for (int c0 = 0; c0 < NBATCH; c0 += Bc) {
    const T* xc   = x    + (size_t)c0 * CC * NN;
    T*       outc = outp + (size_t)c0 * CC * NN;
    ln_naive<T, WANT><<<dim3(Bc * NN), 256, 0, stream>>>(xc, lnw, lnb, xn, flag);
    gemm_naive<T, CC, CC, 0, 0, 0, WANT><<<dim3(32, 49, Bc), 256, 0, stream>>>(xn, Wq, bq, qb, (const T*)nullptr, flag);
    gemm_naive<T, CC, CC, 0, 0, 0, WANT><<<dim3(32, 49, Bc), 256, 0, stream>>>(xn, Wk, bk, kb, (const T*)nullptr, flag);
    gemm_naive<T, CC, CC, 0, 0, 0, WANT><<<dim3(32, 49, Bc), 256, 0, stream>>>(xn, Wv, bv, vb, (const T*)nullptr, flag);
    attn_naive<T, WANT><<<dim3(4, NHEADS, Bc), 256, 0, stream>>>(qb, kb, vb, relb, reli, attn_out, flag);
    gemm_naive<T, CC, CC, 0, 1, 0, WANT><<<dim3(32, 49, Bc), 256, 0, stream>>>(attn_out, Wo, bo, x1, xc, flag);
    gemm_naive<T, FFD, CC, 1, 0, 0, WANT><<<dim3(128, 49, Bc), 256, 0, stream>>>(x1, W1, b1, ff1, (const T*)nullptr, flag);
    gemm_naive<T, CC, FFD, 0, 2, 1, WANT><<<dim3(32, 49, Bc), 256, 0, stream>>>(ff1, W2, b2, outc, x1, flag);
  }
}

extern "C" void kernel_launch(void* const* d_in, const int* in_sizes, int n_in,
                              void* d_out, int out_size, void* d_ws, size_t ws_size,
                              hipStream_t stream)
{
  const size_t TOK   = (size_t)NN * CC;
  const size_t FFTOK = (size_t)NN * FFD;
  const size_t PER_BATCH_BYTES = (4 * TOK + FFTOK) * 4;  // fp32 worst case: 12.85 MB

  int* flag = (int*)d_ws;
  char* buf = (char*)d_ws + 256;
  size_t avail = ws_size > 256 ? ws_size - 256 : 0;

  int Bc = 1;
  for (int c : {16, 8, 4, 2}) {
    if ((size_t)c * PER_BATCH_BYTES <= avail) { Bc = c; break; }
  }

  detect_dtype<<<dim3(1), 256, 0, stream>>>((const unsigned int*)d_in[0], flag);
  run_pipeline<bf16, 1>(d_in, d_out, buf, Bc, flag, stream);
  run_pipeline<float, 0>(d_in, d_out, buf, Bc, flag, stream);
}